// Round 7
// baseline (394.395 us; speedup 1.0000x reference)
//
#include <hip/hip_runtime.h>
#include <cstdint>
#include <cstddef>

// Problem constants
#define SB    1024          // sequence
#define BB    2             // batch
#define HH    768           // hidden
#define NHH   12            // heads
#define HDD   64            // head dim
#define FFF   3072          // ffn dim
#define RR    (BB*SB)       // 2048 token rows
#define NQKV  2304          // fused QKV cols

// u8 quantization for L1 distance: x -> round(x*42.5)+128, clamp [0,255].
#define QSCALE 42.5f

typedef __attribute__((ext_vector_type(8))) short short8;   // 8 x bf16 (4 VGPRs)
typedef __attribute__((ext_vector_type(4))) float f4;       // 4 x f32 accumulator

__device__ __forceinline__ unsigned short f2bf(float f) {
  union { float f; unsigned u; } x; x.f = f;
  unsigned r = x.u + 0x7FFFu + ((x.u >> 16) & 1u);   // RNE
  return (unsigned short)(r >> 16);
}

__device__ __forceinline__ unsigned qz8(float x) {
  int v = (int)rintf(x * QSCALE) + 128;
  v = v < 0 ? 0 : (v > 255 ? 255 : v);
  return (unsigned)v;
}

// async global->LDS, 16B per lane. LDS dest = wave-uniform base + lane*16.
__device__ __forceinline__ void async16(void* lds, const void* g) {
  __builtin_amdgcn_global_load_lds((const __attribute__((address_space(1))) unsigned int*)g,
                                   (__attribute__((address_space(3))) unsigned int*)lds,
                                   16, 0, 0);
}

// ---------------------------------------------------------------------------
// Merged prep: weight transposes (blocks 0..1727), bias concat (1728..1736),
// LN1 rows (1737..3784). One dispatch replaces three.
// ---------------------------------------------------------------------------
__global__ __launch_bounds__(256)
void prep_all(const float* __restrict__ Wq, const float* __restrict__ Wk,
              const float* __restrict__ Wv, const float* __restrict__ Wo,
              const float* __restrict__ W1, const float* __restrict__ W2,
              const float* __restrict__ bq, const float* __restrict__ bk,
              const float* __restrict__ bv,
              const float* __restrict__ hidden, const float* __restrict__ ln1_g,
              const float* __restrict__ ln1_b,
              unsigned short* __restrict__ Wqkv_t, unsigned short* __restrict__ W1t,
              unsigned short* __restrict__ W2t, float* __restrict__ bqkv,
              unsigned short* __restrict__ xb) {
  const int t = blockIdx.x;
  const int tid = threadIdx.x;
  __shared__ float tile[64][65];
  __shared__ float rs[4], rq[4];
  if (t >= 1737) {                     // ---- LN1: one row per block
    const int row = t - 1737;
    const float* x = hidden + (size_t)row * HH;
    float v0 = x[tid], v1 = x[tid + 256], v2 = x[tid + 512];
    float s = v0 + v1 + v2;
    float q = v0 * v0 + v1 * v1 + v2 * v2;
    #pragma unroll
    for (int o = 32; o >= 1; o >>= 1) { s += __shfl_xor(s, o); q += __shfl_xor(q, o); }
    const int w = tid >> 6;
    if ((tid & 63) == 0) { rs[w] = s; rq[w] = q; }
    __syncthreads();
    s = rs[0] + rs[1] + rs[2] + rs[3];
    q = rq[0] + rq[1] + rq[2] + rq[3];
    float mean = s * (1.0f / HH);
    float rstd = rsqrtf(q * (1.0f / HH) - mean * mean + 1e-5f);
    unsigned short* o0 = xb + (size_t)row * HH;
    o0[tid]       = f2bf((v0 - mean) * rstd * ln1_g[tid]       + ln1_b[tid]);
    o0[tid + 256] = f2bf((v1 - mean) * rstd * ln1_g[tid + 256] + ln1_b[tid + 256]);
    o0[tid + 512] = f2bf((v2 - mean) * rstd * ln1_g[tid + 512] + ln1_b[tid + 512]);
    return;
  }
  if (t >= 1728) {                     // ---- bias concat
    int i = (t - 1728) * 256 + tid;
    if (i < NQKV)
      bqkv[i] = (i < HH) ? bq[i] : (i < 2 * HH ? bk[i - HH] : bv[i - 2 * HH]);
    return;
  }
  // ---- transpose+cast tiles
  const float* in; unsigned short* out; int ldin, ldout, r0, c0;
  if (t < 576) {                       // 4x 768x768 -> Wqkv_t (+Wo_t after)
    int m = t / 144, q = t % 144;
    in = m == 0 ? Wq : (m == 1 ? Wk : (m == 2 ? Wv : Wo));
    out = Wqkv_t + (size_t)m * HH * HH;
    ldin = HH; ldout = HH;
    r0 = (q / 12) * 64; c0 = (q % 12) * 64;
  } else if (t < 1152) {               // W1 [768][3072]
    int q = t - 576;
    in = W1; out = W1t; ldin = FFF; ldout = HH;
    r0 = (q % 12) * 64; c0 = (q / 12) * 64;
  } else {                             // W2 [3072][768]
    int q = t - 1152;
    in = W2; out = W2t; ldin = HH; ldout = FFF;
    r0 = (q % 48) * 64; c0 = (q / 48) * 64;
  }
  for (int i = tid; i < 4096; i += 256) {
    int r = i >> 6, c = i & 63;
    tile[r][c] = in[(size_t)(r0 + r) * ldin + c0 + c];
  }
  __syncthreads();
  for (int i = tid; i < 4096; i += 256) {
    int cc = i >> 6, rr = i & 63;
    out[(size_t)(c0 + cc) * ldout + r0 + rr] = f2bf(tile[rr][cc]);
  }
}

// ---------------------------------------------------------------------------
// Fused QKV GEMM, 128x128 tile, 4 waves, depth-2 prefetch / 3 LDS buffers
// with counted vmcnt (no full drain in K-loop; critical at ~1 wave/SIMD).
// Epilogue writes, per column region (blockIdx.x/6):
//   0: Qq u8 [2048][768]            (quantized acc+bias)
//   1: Kq u32 [24 bh][16 dg][1024]  (4 packed u8 dims)
//   2: Vt bf16 [24 bh][64 d][1024]  (transposed)
// All via LDS bounce on the dead staging buffers -> coalesced stores.
// ---------------------------------------------------------------------------
__global__ __launch_bounds__(256)
void gemm_qkv(const unsigned short* __restrict__ A, const unsigned short* __restrict__ Bt,
              const float* __restrict__ bqkv, unsigned* __restrict__ Qq,
              unsigned* __restrict__ Kq, unsigned short* __restrict__ Vt) {
  __shared__ __align__(16) unsigned char smem[49152];   // 3x(8K A + 8K B); bounce <=33.3KB
  unsigned short (*lA)[128 * 32] = (unsigned short (*)[128 * 32])smem;
  unsigned short (*lB)[128 * 32] = (unsigned short (*)[128 * 32])(smem + 24576);
  const unsigned short* Ab = A + (size_t)blockIdx.y * 128 * HH;
  const unsigned short* Bb = Bt + (size_t)blockIdx.x * 128 * HH;
  const int tid = threadIdx.x;
  const int wave = tid >> 6, lane = tid & 63;
  const int wr = wave >> 1, wc = wave & 1;
  const int lo = lane & 15, hi = lane >> 4;

  auto stage = [&](int k0, int buf) {
    #pragma unroll
    for (int i = 0; i < 512; i += 256) {
      int idx = i + tid; int r = idx >> 2, kg = idx & 3;
      async16(&lA[buf][idx * 8], &Ab[(size_t)r * HH + k0 + kg * 8]);
    }
    #pragma unroll
    for (int i = 0; i < 512; i += 256) {
      int idx = i + tid; int r = idx >> 2, kg = idx & 3;
      async16(&lB[buf][idx * 8], &Bb[(size_t)r * HH + k0 + kg * 8]);
    }
  };

  stage(0, 0);
  stage(32, 1);                        // 8 loads/thread outstanding
  f4 acc[4][4] = {};
  for (int it = 0; it < 24; it++) {
    if (it + 1 < 24) {
      asm volatile("s_waitcnt vmcnt(4)" ::: "memory");   // stage(it) done
    } else {
      asm volatile("s_waitcnt vmcnt(0)" ::: "memory");
    }
    __builtin_amdgcn_s_barrier();
    __builtin_amdgcn_sched_barrier(0);
    const int cur = it % 3;
    short8 af[4], bf[4];
    #pragma unroll
    for (int i = 0; i < 4; i++)
      af[i] = *(const short8*)&lA[cur][(wr * 64 + i * 16 + lo) * 32 + hi * 8];
    #pragma unroll
    for (int j = 0; j < 4; j++)
      bf[j] = *(const short8*)&lB[cur][(wc * 64 + j * 16 + lo) * 32 + hi * 8];
    if (it + 2 < 24) stage((it + 2) * 32, (it + 2) % 3);
    #pragma unroll
    for (int i = 0; i < 4; i++)
      #pragma unroll
      for (int j = 0; j < 4; j++)
        acc[i][j] = __builtin_amdgcn_mfma_f32_16x16x32_bf16(af[i], bf[j], acc[i][j], 0, 0, 0);
  }
  __syncthreads();                     // all waves done with staging LDS

  const int reg = blockIdx.x / 6;      // 0 Q, 1 K, 2 V
  const int cb = blockIdx.x * 128;     // global col base
  if (reg < 2) {
    // u8 tile, row stride 132 B (u32 stride 33 -> conflict-free column reads)
    unsigned char* t8 = smem;
    #pragma unroll
    for (int i = 0; i < 4; i++)
      #pragma unroll
      for (int j = 0; j < 4; j++) {
        int col = wc * 64 + j * 16 + lo;
        float bv_ = bqkv[cb + col];
        #pragma unroll
        for (int r = 0; r < 4; r++) {
          int row = wr * 64 + i * 16 + hi * 4 + r;
          t8[row * 132 + col] = (unsigned char)qz8(acc[i][j][r] + bv_);
        }
      }
    __syncthreads();
    const unsigned* t32 = (const unsigned*)smem;
    if (reg == 0) {                    // Qq [token][192 u32]
      #pragma unroll
      for (int i0 = 0; i0 < 4096; i0 += 256) {
        int idx = i0 + tid;
        int cw = idx & 31, rw = idx >> 5;
        int token = blockIdx.y * 128 + rw;
        Qq[(size_t)token * 192 + blockIdx.x * 32 + cw] = t32[rw * 33 + cw];
      }
    } else {                           // Kq [bh][dg][k]
      #pragma unroll
      for (int i0 = 0; i0 < 4096; i0 += 256) {
        int idx = i0 + tid;
        int rw = idx & 127, cw = idx >> 7;
        int token = blockIdx.y * 128 + rw;
        int b = token >> 10, k = token & 1023;
        int dgG = (blockIdx.x - 6) * 32 + cw;
        Kq[(size_t)((b * NHH + (dgG >> 4)) * 16 + (dgG & 15)) * SB + k] = t32[rw * 33 + cw];
      }
    }
  } else {
    // bf16 tile transposed [col][row], row-pair u32 stride 65 (pad)
    unsigned short* t16 = (unsigned short*)smem;
    #pragma unroll
    for (int i = 0; i < 4; i++)
      #pragma unroll
      for (int j = 0; j < 4; j++) {
        int col = wc * 64 + j * 16 + lo;
        float bv_ = bqkv[cb + col];
        #pragma unroll
        for (int r = 0; r < 4; r++) {
          int row = wr * 64 + i * 16 + hi * 4 + r;
          t16[col * 130 + row] = f2bf(acc[i][j][r] + bv_);
        }
      }
    __syncthreads();
    const unsigned* tv = (const unsigned*)smem;
    unsigned* VtU = (unsigned*)Vt;
    #pragma unroll
    for (int i0 = 0; i0 < 8192; i0 += 256) {
      int idx = i0 + tid;
      int rp = idx & 63, cw = idx >> 6;
      int gcol = (blockIdx.x - 12) * 128 + cw;
      int h = gcol >> 6, d = gcol & 63;
      int b = blockIdx.y >> 3;
      VtU[(size_t)((b * NHH + h) * HDD + d) * 512 + (blockIdx.y & 7) * 64 + rp] =
          tv[cw * 65 + rp];
    }
  }
}

// ---------------------------------------------------------------------------
// bf16 MFMA GEMM, C = A[M,K] @ Bt[N,K]^T, depth-2 prefetch / 3 LDS buffers,
// counted vmcnt (never drains to 0 in the main loop), one barrier per K-step.
// MODE 3: bf16 C = gelu_exact(acc + bias) ; 4: f32 C = acc (k-split partial)
// ---------------------------------------------------------------------------
template<int BM, int BN, int WR, int WC, int MODE, int KS>
__global__ __launch_bounds__(WR*WC*64)
void gemm_bt(const unsigned short* __restrict__ A, int ldA,
             const unsigned short* __restrict__ Bt, int ldB,
             void* __restrict__ Cv, int ldC,
             const float* __restrict__ bias,
             int K, long partStride) {
  constexpr int T = WR * WC * 64;
  constexpr int LPT = (BM * 4 + BN * 4) / T;   // async16 per thread per stage
  __shared__ unsigned short lA[3][BM * 32];
  __shared__ unsigned short lB[3][BN * 32];
  const int ks = blockIdx.z;
  const int KH = K / KS;
  const unsigned short* Ab = A + (size_t)blockIdx.y * BM * ldA + (size_t)ks * KH;
  const unsigned short* Bb = Bt + (size_t)blockIdx.x * BN * ldB + (size_t)ks * KH;
  const long cOff = (long)blockIdx.y * BM * ldC + (long)blockIdx.x * BN
                  + (long)ks * partStride;
  const int tid = threadIdx.x;
  const int wave = tid >> 6, lane = tid & 63;
  const int wr = wave / WC, wc = wave % WC;
  const int lo = lane & 15, hi = lane >> 4;

  auto stage = [&](int k0, int buf) {
    #pragma unroll
    for (int i = 0; i < BM * 4; i += T) {
      int idx = i + tid; int r = idx >> 2, kg = idx & 3;
      async16(&lA[buf][idx * 8], &Ab[(size_t)r * ldA + k0 + kg * 8]);
    }
    #pragma unroll
    for (int i = 0; i < BN * 4; i += T) {
      int idx = i + tid; int r = idx >> 2, kg = idx & 3;
      async16(&lB[buf][idx * 8], &Bb[(size_t)r * ldB + k0 + kg * 8]);
    }
  };

  const int nIter = KH / 32;
  stage(0, 0);
  if (nIter > 1) stage(32, 1);
  f4 acc[4][4] = {};
  for (int it = 0; it < nIter; it++) {
    if (it + 1 < nIter) {
      asm volatile("s_waitcnt vmcnt(%0)" :: "n"(LPT) : "memory");  // stage(it) done
    } else {
      asm volatile("s_waitcnt vmcnt(0)" ::: "memory");
    }
    __builtin_amdgcn_s_barrier();
    __builtin_amdgcn_sched_barrier(0);
    const int cur = it % 3;
    short8 af[4], bf[4];
    #pragma unroll
    for (int i = 0; i < 4; i++)
      af[i] = *(const short8*)&lA[cur][(wr * 64 + i * 16 + lo) * 32 + hi * 8];
    #pragma unroll
    for (int j = 0; j < 4; j++)
      bf[j] = *(const short8*)&lB[cur][(wc * 64 + j * 16 + lo) * 32 + hi * 8];
    if (it + 2 < nIter) stage((it + 2) * 32, (it + 2) % 3);
    #pragma unroll
    for (int i = 0; i < 4; i++)
      #pragma unroll
      for (int j = 0; j < 4; j++)
        acc[i][j] = __builtin_amdgcn_mfma_f32_16x16x32_bf16(af[i], bf[j], acc[i][j], 0, 0, 0);
  }
  float* Cf = (float*)Cv;
  unsigned short* Cb = (unsigned short*)Cv;
  const int bc0 = blockIdx.x * BN;
  #pragma unroll
  for (int i = 0; i < 4; i++) {
    #pragma unroll
    for (int j = 0; j < 4; j++) {
      int col = wc * 64 + j * 16 + lo;
      #pragma unroll
      for (int r = 0; r < 4; r++) {
        int row = wr * 64 + i * 16 + hi * 4 + r;
        size_t idx = (size_t)cOff + (size_t)row * ldC + col;
        float v = acc[i][j][r];
        if constexpr (MODE == 3) {
          float tt = v + bias[bc0 + col];
          Cb[idx] = f2bf(0.5f * tt * (1.0f + erff(tt * 0.70710678118654752f)));
        } else {
          Cf[idx] = v;   // k-split partial
        }
      }
    }
  }
}

// ---------------------------------------------------------------------------
// Fused split-K reduce + bias + residual + LayerNorm.
// attnOut = sum_{s<4} p_s + bias + res ; out = LN(attnOut)*g + b (bf16).
// One block per row of 768.
// ---------------------------------------------------------------------------
__global__ __launch_bounds__(256)
void reduce_ln(const float* __restrict__ p, const float* __restrict__ bias,
               const float* __restrict__ res, const float* __restrict__ g,
               const float* __restrict__ bb, float* __restrict__ attnOut,
               unsigned short* __restrict__ out) {
  const int row = blockIdx.x, tid = threadIdx.x;
  const size_t rb = (size_t)row * HH;
  float v[3]; float s = 0.f, q = 0.f;
  #pragma unroll
  for (int j = 0; j < 3; j++) {
    int c = tid + j * 256;
    size_t idx = rb + c;
    float a = p[idx] + p[(size_t)RR * HH + idx] + p[2 * (size_t)RR * HH + idx]
            + p[3 * (size_t)RR * HH + idx] + bias[c] + res[idx];
    attnOut[idx] = a;
    v[j] = a; s += a; q += a * a;
  }
  #pragma unroll
  for (int o = 32; o >= 1; o >>= 1) { s += __shfl_xor(s, o); q += __shfl_xor(q, o); }
  __shared__ float rs[4], rq[4];
  const int w = tid >> 6;
  if ((tid & 63) == 0) { rs[w] = s; rq[w] = q; }
  __syncthreads();
  s = rs[0] + rs[1] + rs[2] + rs[3];
  q = rq[0] + rq[1] + rq[2] + rq[3];
  float mean = s * (1.0f / HH);
  float rstd = rsqrtf(q * (1.0f / HH) - mean * mean + 1e-5f);
  #pragma unroll
  for (int j = 0; j < 3; j++) {
    int c = tid + j * 256;
    out[rb + c] = f2bf((v[j] - mean) * rstd * g[c] + bb[c]);
  }
}

// out f32 = sum_{s<4} part_s + bias[col] + res, vectorized x4 (row len 768)
__global__ __launch_bounds__(256)
void reduce4_bias_res(const float* __restrict__ p, const float* __restrict__ bias,
                      const float* __restrict__ res, float* __restrict__ out) {
  int i = (blockIdx.x * 256 + threadIdx.x) * 4;
  int col = i % HH;
  float4 a = *(const float4*)(p + i);
  #pragma unroll
  for (int s = 1; s < 4; s++) {
    float4 b = *(const float4*)(p + (size_t)s * RR * HH + i);
    a.x += b.x; a.y += b.y; a.z += b.z; a.w += b.w;
  }
  float4 bb = *(const float4*)(bias + col);
  float4 r = *(const float4*)(res + i);
  float4 o;
  o.x = a.x + bb.x + r.x;
  o.y = a.y + bb.y + r.y;
  o.z = a.z + bb.z + r.z;
  o.w = a.w + bb.w + r.w;
  *(float4*)(out + i) = o;
}

// ---------------------------------------------------------------------------
// Fused L1-distance (v_sad_u8) + softmax + PV MFMA, v3:
// Wave w owns k-slice [w*128, w*128+128) for ALL 16 q rows (L1 distance has
// no k-reduction, so the k-split mapping is free). K slice lives in 32 VGPRs,
// loaded ONCE from global (64 KB/block total vs 512 KB with the q-split
// mapping). Softmax is cross-wave: wave-local shfl reduce -> 8 partials in
// LDS -> combine. P stored bf16 in LDS with XOR swizzle (verified in R6:
// bank conflicts 5.5M -> 786K); PV via waves 0..3 as before.
// ---------------------------------------------------------------------------
#define DQ 16
__global__ __launch_bounds__(512)
void dist_softmax_pv(const unsigned* __restrict__ Qq, const unsigned* __restrict__ Kq,
                     const unsigned short* __restrict__ Vt,
                     const float* __restrict__ lam_p,
                     float* __restrict__ attnF, unsigned short* __restrict__ ctx) {
  __shared__ __align__(16) unsigned short lp[DQ * SB];   // 32 KB: P bf16, swizzled
  __shared__ unsigned lq[DQ * 16];                       // 1 KB: [row][dg]
  __shared__ __align__(16) float red[2][DQ][8];          // 1 KB: max/sum partials
  const int bh = blockIdx.y;           // 0..23
  const int q0 = blockIdx.x * DQ;
  const int b = bh / NHH, h = bh % NHH;
  const int tid = threadIdx.x;
  const int w = tid >> 6, lane = tid & 63;
  const int lo = lane & 15, hi = lane >> 4;

  // load pre-quantized Q tile: 16 rows x 16 dgroups
  if (tid < 256) {
    int r = tid >> 4, dg = tid & 15;
    lq[r * 16 + dg] = Qq[(size_t)(b * SB + q0 + r) * 192 + h * 16 + dg];
  }

  // load K slice into registers: lane covers k = w*128 + lane*2 + {0,1}
  const unsigned* Ks = Kq + (size_t)bh * 16 * SB + w * 128 + lane * 2;
  uint2 kd[16];
  #pragma unroll
  for (int dg = 0; dg < 16; dg++)
    kd[dg] = *(const uint2*)&Ks[(size_t)dg * SB];        // 16 independent loads
  __syncthreads();   // lq ready

  // SAD: per q row, accumulate over 16 dgroups into 2 k-scores per lane
  const float kscl = -lam_p[0] * 0.125f / QSCALE;
  float sc0[16], sc1[16];
  #pragma unroll
  for (int r = 0; r < 16; r++) {
    uint4 qa = *(const uint4*)&lq[r * 16];        // broadcast reads
    uint4 qb = *(const uint4*)&lq[r * 16 + 4];
    uint4 qc = *(const uint4*)&lq[r * 16 + 8];
    uint4 qd = *(const uint4*)&lq[r * 16 + 12];
    unsigned a0 = 0, a1 = 0;
    a0 = __builtin_amdgcn_sad_u8(qa.x, kd[0].x, a0);  a1 = __builtin_amdgcn_sad_u8(qa.x, kd[0].y, a1);
    a0 = __builtin_amdgcn_sad_u8(qa.y, kd[1].x, a0);  a1 = __builtin_amdgcn_sad_u8(qa.y, kd[1].y, a1);
    a0 = __builtin_amdgcn_sad_u8(qa.z, kd[2].x, a0);  a1 = __builtin_amdgcn_sad_u8(qa.z, kd[2].y, a1);
    a0 = __builtin_amdgcn_sad_u8(qa.w, kd[3].x, a0);  a1 = __builtin_amdgcn_sad_u8(qa.w, kd[3].y, a1);
    a0 = __builtin_amdgcn_sad_u8(qb.x, kd[4].x, a0);  a1 = __builtin_amdgcn_sad_u8(qb.x, kd[4].y, a1);
    a0 = __builtin_amdgcn_sad_u8(qb.y, kd[5].x, a0);  a1 = __builtin_amdgcn_sad_u8(qb.y, kd[5].y, a1);
    a0 = __builtin_amdgcn_sad_u8(qb.z, kd[6].x, a0);  a1 = __builtin_amdgcn_sad_u8(qb.z, kd[6].y, a1);
    a0 = __builtin_amdgcn_sad_u8(qb.w, kd[7].x, a0);  a1 = __builtin_amdgcn_sad_u8(qb.w, kd[7].y, a1);
    a0 = __builtin_amdgcn_sad_u8(qc.x, kd[8].x, a0);  a1 = __builtin_amdgcn_sad_u8(qc.x, kd[8].y, a1);
    a0 = __builtin_amdgcn_sad_u8(qc.y, kd[9].x, a0);  a1 = __builtin_amdgcn_sad_u8(qc.y, kd[9].y, a1);
    a0 = __builtin_amdgcn_sad_u8(qc.z, kd[10].x, a0); a1 = __builtin_amdgcn_sad_u8(qc.z, kd[10].y, a1);
    a0 = __builtin_amdgcn_sad_u8(qc.w, kd[11].x, a0); a1 = __builtin_amdgcn_sad_u8(qc.w, kd[11].y, a1);
    a0 = __builtin_amdgcn_sad_u8(qd.x, kd[12].x, a0); a1 = __builtin_amdgcn_sad_u8(qd.x, kd[12].y, a1);
    a0 = __builtin_amdgcn_sad_u8(qd.y, kd[13].x, a0); a1 = __builtin_amdgcn_sad_u8(qd.y, kd[13].y, a1);
    a0 = __builtin_amdgcn_sad_u8(qd.z, kd[14].x, a0); a1 = __builtin_amdgcn_sad_u8(qd.z, kd[14].y, a1);
    a0 = __builtin_amdgcn_sad_u8(qd.w, kd[15].x, a0); a1 = __builtin_amdgcn_sad_u8(qd.w, kd[15].y, a1);
    sc0[r] = (float)a0 * kscl;
    sc1[r] = (float)a1 * kscl;
  }

  // wave-local max per row -> partials in LDS
  #pragma unroll
  for (int r = 0; r < 16; r++) {
    float m = fmaxf(sc0[r], sc1[r]);
    #pragma unroll
    for (int off = 1; off < 64; off <<= 1) m = fmaxf(m, __shfl_xor(m, off));
    if (lane == 0) red[0][r][w] = m;
  }
  __syncthreads();

  // combine global max per row; exp + wave-local sum -> partials
  float mx[16];
  #pragma unroll
  for (int r = 0; r < 16; r++) {
    float4 a = *(const float4*)&red[0][r][0];
    float4 c = *(const float4*)&red[0][r][4];
    mx[r] = fmaxf(fmaxf(fmaxf(a.x, a.y), fmaxf(a.z, a.w)),
                  fmaxf(fmaxf(c.x, c.y), fmaxf(c.z, c.w)));
  }
  #pragma unroll
  for (int r = 0; r < 16; r++) {
    sc0[r] = __expf(sc0[r] - mx[r]);
    sc1[r] = __expf(sc1[r] - mx[r]);
    float s = sc0[r] + sc1[r];
    #pragma unroll
    for (int off = 1; off < 64; off <<= 1) s += __shfl_xor(s, off);
    if (lane == 0) red[1][r][w] = s;
  }
  __syncthreads();

  // finalize: write attn f32 + P bf16 (swizzled) into LDS
  const size_t gbase = (size_t)bh * SB * SB + (size_t)q0 * SB + w * 128 + lane * 2;
  #pragma unroll
  for (int r = 0; r < 16; r++) {
    float4 a = *(const float4*)&red[1][r][0];
    float4 c = *(const float4*)&red[1][r][4];
    float rinv = 1.0f / (a.x + a.y + a.z + a.w + c.x + c.y + c.z + c.w);
    float p0 = sc0[r] * rinv, p1 = sc1[r] * rinv;
    float2 pw; pw.x = p0; pw.y = p1;
    *(float2*)&attnF[gbase + (size_t)r * SB] = pw;
    unsigned pk = (unsigned)f2bf(p0) | ((unsigned)f2bf(p1) << 16);
    unsigned idx = (unsigned)(r * SB + w * 128 + lane * 2) ^ (unsigned)((r & 7) << 3);
    *(unsigned*)&lp[idx] = pk;
  }
  __syncthreads();   // P complete in LDS

  // PV: waves 0..3; wave w covers cols w*16..+15 (d), all 16 q rows, K=1024.
  if (w < 4) {
    const unsigned short* Vb = Vt + ((size_t)bh * HDD + w * 16 + lo) * SB + hi * 8;
    const unsigned pswz = (unsigned)((lo & 7) << 3);
    const unsigned pbase = (unsigned)(lo * SB + hi * 8);
    f4 cacc = {0.f, 0.f, 0.f, 0.f};
    #pragma unroll
    for (int k0 = 0; k0 < SB; k0 += 32) {
      short8 af = *(const short8*)&lp[(pbase + k0) ^ pswz];   // A: P[m=lo][k]
      short8 bf = *(const short8*)(Vb + k0);                  // B: Vt[n=col][k]
      cacc = __builtin_amdgcn_mfma_f32_16x16x32_bf16(af, bf, cacc, 0, 0, 0);
    }
    // D: col=lane&15 -> d = w*16+lo ; row=(lane>>4)*4+r -> q row
    unsigned short* cb = ctx + (size_t)(b * SB + q0 + hi * 4) * HH + h * HDD + w * 16 + lo;
    #pragma unroll
    for (int r = 0; r < 4; r++) cb[(size_t)r * HH] = f2bf(cacc[r]);
  }
}

// ---------------------------------------------------------------------------
extern "C" void kernel_launch(void* const* d_in, const int* in_sizes, int n_in,
                              void* d_out, int out_size, void* d_ws, size_t ws_size,
                              hipStream_t stream) {
  (void)in_sizes; (void)n_in; (void)out_size; (void)ws_size;
  const float* hidden = (const float*)d_in[0];
  const float* ln1_g  = (const float*)d_in[1];
  const float* ln1_b  = (const float*)d_in[2];
  const float* Wq     = (const float*)d_in[3];
  const float* bq     = (const float*)d_in[4];
  const float* Wk     = (const float*)d_in[5];
  const float* bk     = (const float*)d_in[6];
  const float* Wv     = (const float*)d_in[7];
  const float* bv     = (const float*)d_in[8];
  const float* Wo     = (const float*)d_in[9];
  const float* bo     = (const float*)d_in[10];
  const float* lam    = (const float*)d_in[11];
  const float* ln2_g  = (const float*)d_in[12];
  const float* ln2_b  = (const float*)d_in[13];
  const float* W1     = (const float*)d_in[14];
  const float* b1     = (const float*)d_in[15];
  const float* W2     = (const float*)d_in[16];
  const float* b2     = (const float*)d_in[17];

  float* out0  = (float*)d_out;                     // [2,1024,768]
  float* attnF = out0 + (size_t)RR * HH;            // [2,12,1024,1024]

  // workspace carve-up (256B aligned)
  char* w = (char*)d_ws;
  auto alloc = [&](size_t bytes) { char* p = w; w += (bytes + 255) & ~(size_t)255; return p; };
  unsigned short* xb      = (unsigned short*)alloc((size_t)RR * HH * 2);       // LN1 out bf16
  unsigned short* Wqkv_t  = (unsigned short*)alloc((size_t)NQKV * HH * 2);     // [2304][768]
  unsigned short* Wo_t    = (unsigned short*)alloc((size_t)HH * HH * 2);       // contiguous after Wqkv_t!
  unsigned short* W1t     = (unsigned short*)alloc((size_t)FFF * HH * 2);      // [3072][768]
  unsigned short* W2t     = (unsigned short*)alloc((size_t)HH * FFF * 2);      // [768][3072]
  float*          bqkv    = (float*)alloc((size_t)NQKV * 4);
  unsigned*       Qq      = (unsigned*)alloc((size_t)RR * 192 * 4);            // u8 [2048][768]
  unsigned*       Kq      = (unsigned*)alloc((size_t)BB * NHH * 16 * SB * 4);  // u8x4 [24][16][1024]
  unsigned short* Vt      = (unsigned short*)alloc((size_t)BB * NHH * HDD * SB * 2); // [24][64][1024]
  unsigned short* ctx     = (unsigned short*)alloc((size_t)RR * HH * 2);       // PV out bf16
  float*          attnOut = (float*)alloc((size_t)RR * HH * 4);                // attn block out f32
  unsigned short* h1      = (unsigned short*)alloc((size_t)RR * FFF * 2);      // FFN1 out bf16
  float*          gPart   = (float*)alloc((size_t)4 * RR * HH * 4);            // split-K partials x4
  unsigned short* y2      = Vt;                     // alias: Vt dead after dist
  (void)Wo_t;

  // ---- 1. prep: weight transposes + bias concat + LN1 (one dispatch)
  prep_all<<<dim3(1737 + RR), 256, 0, stream>>>(Wq, Wk, Wv, Wo, W1, W2, bq, bk, bv,
                                                hidden, ln1_g, ln1_b,
                                                Wqkv_t, W1t, W2t, bqkv, xb);

  // ---- 2. fused QKV GEMM with quantize/transpose epilogue (288 blocks)
  gemm_qkv<<<dim3(NQKV / 128, RR / 128), 256, 0, stream>>>(
      xb, Wqkv_t, bqkv, Qq, Kq, Vt);

  // ---- 3. L1 distance + softmax + PV -> attn f32 (d_out) + ctx bf16
  dist_softmax_pv<<<dim3(SB / DQ, BB * NHH), 512, 0, stream>>>(
      Qq, Kq, Vt, lam, attnF, ctx);

  // ---- 4. output proj, 128x128 split-K x4 (384 blocks): ctx@Wo -> partials
  gemm_bt<128, 128, 2, 2, 4, 4><<<dim3(HH / 128, RR / 128, 4), 256, 0, stream>>>(
      ctx, HH, Wqkv_t + (size_t)3 * HH * HH, HH, gPart, HH,
      nullptr, HH, (long)RR * HH);

  // ---- 5. fused reduce(+bo+hidden) + LN2 -> attnOut f32 + y2 bf16
  reduce_ln<<<dim3(RR), 256, 0, stream>>>(gPart, bo, hidden, ln2_g, ln2_b,
                                          attnOut, y2);

  // ---- 6. FFN1: gelu(y2@W1 + b1) -> bf16 (384 blocks, 128x128)
  gemm_bt<128, 128, 2, 2, 3, 1><<<dim3(FFF / 128, RR / 128, 1), 256, 0, stream>>>(
      y2, HH, W1t, HH, h1, FFF, b1, HH, 0);

  // ---- 7. FFN2, 128x128 split-K x4 (384 blocks): h1@W2 -> partials
  gemm_bt<128, 128, 2, 2, 4, 4><<<dim3(HH / 128, RR / 128, 4), 256, 0, stream>>>(
      h1, FFF, W2t, FFF, gPart, HH, nullptr, FFF, (long)RR * HH);

  // ---- 8. final reduce + b2 + attnOut -> out0
  reduce4_bias_res<<<dim3(RR * HH / 1024), 256, 0, stream>>>(gPart, b2, attnOut, out0);
}

// Round 8
// 285.454 us; speedup vs baseline: 1.3816x; 1.3816x over previous
//
#include <hip/hip_runtime.h>
#include <cstdint>
#include <cstddef>

// Problem constants
#define SB    1024          // sequence
#define BB    2             // batch
#define HH    768           // hidden
#define NHH   12            // heads
#define HDD   64            // head dim
#define FFF   3072          // ffn dim
#define RR    (BB*SB)       // 2048 token rows
#define NQKV  2304          // fused QKV cols

// u8 quantization for L1 distance: x -> round(x*42.5)+128, clamp [0,255].
#define QSCALE 42.5f

typedef __attribute__((ext_vector_type(8))) short short8;   // 8 x bf16 (4 VGPRs)
typedef __attribute__((ext_vector_type(4))) float f4;       // 4 x f32 accumulator

__device__ __forceinline__ unsigned short f2bf(float f) {
  union { float f; unsigned u; } x; x.f = f;
  unsigned r = x.u + 0x7FFFu + ((x.u >> 16) & 1u);   // RNE
  return (unsigned short)(r >> 16);
}

__device__ __forceinline__ unsigned qz8(float x) {
  int v = (int)rintf(x * QSCALE) + 128;
  v = v < 0 ? 0 : (v > 255 ? 255 : v);
  return (unsigned)v;
}

// async global->LDS, 16B per lane. LDS dest = wave-uniform base + lane*16.
__device__ __forceinline__ void async16(void* lds, const void* g) {
  __builtin_amdgcn_global_load_lds((const __attribute__((address_space(1))) unsigned int*)g,
                                   (__attribute__((address_space(3))) unsigned int*)lds,
                                   16, 0, 0);
}

// ---------------------------------------------------------------------------
// Merged prep: weight transposes (blocks 0..1727), bias concat (1728..1736),
// LN1 rows (1737..3784). One dispatch replaces three.
// ---------------------------------------------------------------------------
__global__ __launch_bounds__(256)
void prep_all(const float* __restrict__ Wq, const float* __restrict__ Wk,
              const float* __restrict__ Wv, const float* __restrict__ Wo,
              const float* __restrict__ W1, const float* __restrict__ W2,
              const float* __restrict__ bq, const float* __restrict__ bk,
              const float* __restrict__ bv,
              const float* __restrict__ hidden, const float* __restrict__ ln1_g,
              const float* __restrict__ ln1_b,
              unsigned short* __restrict__ Wqkv_t, unsigned short* __restrict__ W1t,
              unsigned short* __restrict__ W2t, float* __restrict__ bqkv,
              unsigned short* __restrict__ xb) {
  const int t = blockIdx.x;
  const int tid = threadIdx.x;
  __shared__ float tile[64][65];
  __shared__ float rs[4], rq[4];
  if (t >= 1737) {                     // ---- LN1: one row per block
    const int row = t - 1737;
    const float* x = hidden + (size_t)row * HH;
    float v0 = x[tid], v1 = x[tid + 256], v2 = x[tid + 512];
    float s = v0 + v1 + v2;
    float q = v0 * v0 + v1 * v1 + v2 * v2;
    #pragma unroll
    for (int o = 32; o >= 1; o >>= 1) { s += __shfl_xor(s, o); q += __shfl_xor(q, o); }
    const int w = tid >> 6;
    if ((tid & 63) == 0) { rs[w] = s; rq[w] = q; }
    __syncthreads();
    s = rs[0] + rs[1] + rs[2] + rs[3];
    q = rq[0] + rq[1] + rq[2] + rq[3];
    float mean = s * (1.0f / HH);
    float rstd = rsqrtf(q * (1.0f / HH) - mean * mean + 1e-5f);
    unsigned short* o0 = xb + (size_t)row * HH;
    o0[tid]       = f2bf((v0 - mean) * rstd * ln1_g[tid]       + ln1_b[tid]);
    o0[tid + 256] = f2bf((v1 - mean) * rstd * ln1_g[tid + 256] + ln1_b[tid + 256]);
    o0[tid + 512] = f2bf((v2 - mean) * rstd * ln1_g[tid + 512] + ln1_b[tid + 512]);
    return;
  }
  if (t >= 1728) {                     // ---- bias concat
    int i = (t - 1728) * 256 + tid;
    if (i < NQKV)
      bqkv[i] = (i < HH) ? bq[i] : (i < 2 * HH ? bk[i - HH] : bv[i - 2 * HH]);
    return;
  }
  // ---- transpose+cast tiles
  const float* in; unsigned short* out; int ldin, ldout, r0, c0;
  if (t < 576) {                       // 4x 768x768 -> Wqkv_t (+Wo_t after)
    int m = t / 144, q = t % 144;
    in = m == 0 ? Wq : (m == 1 ? Wk : (m == 2 ? Wv : Wo));
    out = Wqkv_t + (size_t)m * HH * HH;
    ldin = HH; ldout = HH;
    r0 = (q / 12) * 64; c0 = (q % 12) * 64;
  } else if (t < 1152) {               // W1 [768][3072]
    int q = t - 576;
    in = W1; out = W1t; ldin = FFF; ldout = HH;
    r0 = (q % 12) * 64; c0 = (q / 12) * 64;
  } else {                             // W2 [3072][768]
    int q = t - 1152;
    in = W2; out = W2t; ldin = HH; ldout = FFF;
    r0 = (q % 48) * 64; c0 = (q / 48) * 64;
  }
  for (int i = tid; i < 4096; i += 256) {
    int r = i >> 6, c = i & 63;
    tile[r][c] = in[(size_t)(r0 + r) * ldin + c0 + c];
  }
  __syncthreads();
  for (int i = tid; i < 4096; i += 256) {
    int cc = i >> 6, rr = i & 63;
    out[(size_t)(c0 + cc) * ldout + r0 + rr] = f2bf(tile[rr][cc]);
  }
}

// ---------------------------------------------------------------------------
// Fused QKV GEMM, 128x128 tile, 4 waves, depth-2 prefetch / 3 LDS buffers
// with counted vmcnt (no full drain in K-loop; critical at ~1 wave/SIMD).
// Epilogue writes, per column region (blockIdx.x/6):
//   0: Qq u8 [2048][768]            (quantized acc+bias)
//   1: Kq u32 [24 bh][16 dg][1024]  (4 packed u8 dims)
//   2: Vt bf16 [24 bh][64 d][1024]  (transposed)
// All via LDS bounce on the dead staging buffers -> coalesced stores.
// ---------------------------------------------------------------------------
__global__ __launch_bounds__(256)
void gemm_qkv(const unsigned short* __restrict__ A, const unsigned short* __restrict__ Bt,
              const float* __restrict__ bqkv, unsigned* __restrict__ Qq,
              unsigned* __restrict__ Kq, unsigned short* __restrict__ Vt) {
  __shared__ __align__(16) unsigned char smem[49152];   // 3x(8K A + 8K B); bounce <=33.3KB
  unsigned short (*lA)[128 * 32] = (unsigned short (*)[128 * 32])smem;
  unsigned short (*lB)[128 * 32] = (unsigned short (*)[128 * 32])(smem + 24576);
  const unsigned short* Ab = A + (size_t)blockIdx.y * 128 * HH;
  const unsigned short* Bb = Bt + (size_t)blockIdx.x * 128 * HH;
  const int tid = threadIdx.x;
  const int wave = tid >> 6, lane = tid & 63;
  const int wr = wave >> 1, wc = wave & 1;
  const int lo = lane & 15, hi = lane >> 4;

  auto stage = [&](int k0, int buf) {
    #pragma unroll
    for (int i = 0; i < 512; i += 256) {
      int idx = i + tid; int r = idx >> 2, kg = idx & 3;
      async16(&lA[buf][idx * 8], &Ab[(size_t)r * HH + k0 + kg * 8]);
    }
    #pragma unroll
    for (int i = 0; i < 512; i += 256) {
      int idx = i + tid; int r = idx >> 2, kg = idx & 3;
      async16(&lB[buf][idx * 8], &Bb[(size_t)r * HH + k0 + kg * 8]);
    }
  };

  stage(0, 0);
  stage(32, 1);                        // 8 loads/thread outstanding
  f4 acc[4][4] = {};
  for (int it = 0; it < 24; it++) {
    if (it + 1 < 24) {
      asm volatile("s_waitcnt vmcnt(4)" ::: "memory");   // stage(it) done
    } else {
      asm volatile("s_waitcnt vmcnt(0)" ::: "memory");
    }
    __builtin_amdgcn_s_barrier();
    __builtin_amdgcn_sched_barrier(0);
    const int cur = it % 3;
    short8 af[4], bf[4];
    #pragma unroll
    for (int i = 0; i < 4; i++)
      af[i] = *(const short8*)&lA[cur][(wr * 64 + i * 16 + lo) * 32 + hi * 8];
    #pragma unroll
    for (int j = 0; j < 4; j++)
      bf[j] = *(const short8*)&lB[cur][(wc * 64 + j * 16 + lo) * 32 + hi * 8];
    if (it + 2 < 24) stage((it + 2) * 32, (it + 2) % 3);
    #pragma unroll
    for (int i = 0; i < 4; i++)
      #pragma unroll
      for (int j = 0; j < 4; j++)
        acc[i][j] = __builtin_amdgcn_mfma_f32_16x16x32_bf16(af[i], bf[j], acc[i][j], 0, 0, 0);
  }
  __syncthreads();                     // all waves done with staging LDS

  const int reg = blockIdx.x / 6;      // 0 Q, 1 K, 2 V
  const int cb = blockIdx.x * 128;     // global col base
  if (reg < 2) {
    // u8 tile, row stride 132 B (u32 stride 33 -> conflict-free column reads)
    unsigned char* t8 = smem;
    #pragma unroll
    for (int i = 0; i < 4; i++)
      #pragma unroll
      for (int j = 0; j < 4; j++) {
        int col = wc * 64 + j * 16 + lo;
        float bv_ = bqkv[cb + col];
        #pragma unroll
        for (int r = 0; r < 4; r++) {
          int row = wr * 64 + i * 16 + hi * 4 + r;
          t8[row * 132 + col] = (unsigned char)qz8(acc[i][j][r] + bv_);
        }
      }
    __syncthreads();
    const unsigned* t32 = (const unsigned*)smem;
    if (reg == 0) {                    // Qq [token][192 u32]
      #pragma unroll
      for (int i0 = 0; i0 < 4096; i0 += 256) {
        int idx = i0 + tid;
        int cw = idx & 31, rw = idx >> 5;
        int token = blockIdx.y * 128 + rw;
        Qq[(size_t)token * 192 + blockIdx.x * 32 + cw] = t32[rw * 33 + cw];
      }
    } else {                           // Kq [bh][dg][k]
      #pragma unroll
      for (int i0 = 0; i0 < 4096; i0 += 256) {
        int idx = i0 + tid;
        int rw = idx & 127, cw = idx >> 7;
        int token = blockIdx.y * 128 + rw;
        int b = token >> 10, k = token & 1023;
        int dgG = (blockIdx.x - 6) * 32 + cw;
        Kq[(size_t)((b * NHH + (dgG >> 4)) * 16 + (dgG & 15)) * SB + k] = t32[rw * 33 + cw];
      }
    }
  } else {
    // bf16 tile transposed [col][row], row-pair u32 stride 65 (pad)
    unsigned short* t16 = (unsigned short*)smem;
    #pragma unroll
    for (int i = 0; i < 4; i++)
      #pragma unroll
      for (int j = 0; j < 4; j++) {
        int col = wc * 64 + j * 16 + lo;
        float bv_ = bqkv[cb + col];
        #pragma unroll
        for (int r = 0; r < 4; r++) {
          int row = wr * 64 + i * 16 + hi * 4 + r;
          t16[col * 130 + row] = f2bf(acc[i][j][r] + bv_);
        }
      }
    __syncthreads();
    const unsigned* tv = (const unsigned*)smem;
    unsigned* VtU = (unsigned*)Vt;
    #pragma unroll
    for (int i0 = 0; i0 < 8192; i0 += 256) {
      int idx = i0 + tid;
      int rp = idx & 63, cw = idx >> 6;
      int gcol = (blockIdx.x - 12) * 128 + cw;
      int h = gcol >> 6, d = gcol & 63;
      int b = blockIdx.y >> 3;
      VtU[(size_t)((b * NHH + h) * HDD + d) * 512 + (blockIdx.y & 7) * 64 + rp] =
          tv[cw * 65 + rp];
    }
  }
}

// ---------------------------------------------------------------------------
// bf16 MFMA GEMM, C = A[M,K] @ Bt[N,K]^T, depth-2 prefetch / 3 LDS buffers,
// counted vmcnt (never drains to 0 in the main loop), one barrier per K-step.
// MODE 3: bf16 C = gelu_exact(acc + bias) ; 4: f32 C = acc (k-split partial)
// ---------------------------------------------------------------------------
template<int BM, int BN, int WR, int WC, int MODE, int KS>
__global__ __launch_bounds__(WR*WC*64)
void gemm_bt(const unsigned short* __restrict__ A, int ldA,
             const unsigned short* __restrict__ Bt, int ldB,
             void* __restrict__ Cv, int ldC,
             const float* __restrict__ bias,
             int K, long partStride) {
  constexpr int T = WR * WC * 64;
  constexpr int LPT = (BM * 4 + BN * 4) / T;   // async16 per thread per stage
  __shared__ unsigned short lA[3][BM * 32];
  __shared__ unsigned short lB[3][BN * 32];
  const int ks = blockIdx.z;
  const int KH = K / KS;
  const unsigned short* Ab = A + (size_t)blockIdx.y * BM * ldA + (size_t)ks * KH;
  const unsigned short* Bb = Bt + (size_t)blockIdx.x * BN * ldB + (size_t)ks * KH;
  const long cOff = (long)blockIdx.y * BM * ldC + (long)blockIdx.x * BN
                  + (long)ks * partStride;
  const int tid = threadIdx.x;
  const int wave = tid >> 6, lane = tid & 63;
  const int wr = wave / WC, wc = wave % WC;
  const int lo = lane & 15, hi = lane >> 4;

  auto stage = [&](int k0, int buf) {
    #pragma unroll
    for (int i = 0; i < BM * 4; i += T) {
      int idx = i + tid; int r = idx >> 2, kg = idx & 3;
      async16(&lA[buf][idx * 8], &Ab[(size_t)r * ldA + k0 + kg * 8]);
    }
    #pragma unroll
    for (int i = 0; i < BN * 4; i += T) {
      int idx = i + tid; int r = idx >> 2, kg = idx & 3;
      async16(&lB[buf][idx * 8], &Bb[(size_t)r * ldB + k0 + kg * 8]);
    }
  };

  const int nIter = KH / 32;
  stage(0, 0);
  if (nIter > 1) stage(32, 1);
  f4 acc[4][4] = {};
  for (int it = 0; it < nIter; it++) {
    if (it + 1 < nIter) {
      asm volatile("s_waitcnt vmcnt(%0)" :: "n"(LPT) : "memory");  // stage(it) done
    } else {
      asm volatile("s_waitcnt vmcnt(0)" ::: "memory");
    }
    __builtin_amdgcn_s_barrier();
    __builtin_amdgcn_sched_barrier(0);
    const int cur = it % 3;
    short8 af[4], bf[4];
    #pragma unroll
    for (int i = 0; i < 4; i++)
      af[i] = *(const short8*)&lA[cur][(wr * 64 + i * 16 + lo) * 32 + hi * 8];
    #pragma unroll
    for (int j = 0; j < 4; j++)
      bf[j] = *(const short8*)&lB[cur][(wc * 64 + j * 16 + lo) * 32 + hi * 8];
    if (it + 2 < nIter) stage((it + 2) * 32, (it + 2) % 3);
    #pragma unroll
    for (int i = 0; i < 4; i++)
      #pragma unroll
      for (int j = 0; j < 4; j++)
        acc[i][j] = __builtin_amdgcn_mfma_f32_16x16x32_bf16(af[i], bf[j], acc[i][j], 0, 0, 0);
  }
  float* Cf = (float*)Cv;
  unsigned short* Cb = (unsigned short*)Cv;
  const int bc0 = blockIdx.x * BN;
  #pragma unroll
  for (int i = 0; i < 4; i++) {
    #pragma unroll
    for (int j = 0; j < 4; j++) {
      int col = wc * 64 + j * 16 + lo;
      #pragma unroll
      for (int r = 0; r < 4; r++) {
        int row = wr * 64 + i * 16 + hi * 4 + r;
        size_t idx = (size_t)cOff + (size_t)row * ldC + col;
        float v = acc[i][j][r];
        if constexpr (MODE == 3) {
          float tt = v + bias[bc0 + col];
          Cb[idx] = f2bf(0.5f * tt * (1.0f + erff(tt * 0.70710678118654752f)));
        } else {
          Cf[idx] = v;   // k-split partial
        }
      }
    }
  }
}

// ---------------------------------------------------------------------------
// Fused split-K reduce + bias + residual + LayerNorm.
// attnOut = sum_{s<4} p_s + bias + res ; out = LN(attnOut)*g + b (bf16).
// One block per row of 768.
// ---------------------------------------------------------------------------
__global__ __launch_bounds__(256)
void reduce_ln(const float* __restrict__ p, const float* __restrict__ bias,
               const float* __restrict__ res, const float* __restrict__ g,
               const float* __restrict__ bb, float* __restrict__ attnOut,
               unsigned short* __restrict__ out) {
  const int row = blockIdx.x, tid = threadIdx.x;
  const size_t rb = (size_t)row * HH;
  float v[3]; float s = 0.f, q = 0.f;
  #pragma unroll
  for (int j = 0; j < 3; j++) {
    int c = tid + j * 256;
    size_t idx = rb + c;
    float a = p[idx] + p[(size_t)RR * HH + idx] + p[2 * (size_t)RR * HH + idx]
            + p[3 * (size_t)RR * HH + idx] + bias[c] + res[idx];
    attnOut[idx] = a;
    v[j] = a; s += a; q += a * a;
  }
  #pragma unroll
  for (int o = 32; o >= 1; o >>= 1) { s += __shfl_xor(s, o); q += __shfl_xor(q, o); }
  __shared__ float rs[4], rq[4];
  const int w = tid >> 6;
  if ((tid & 63) == 0) { rs[w] = s; rq[w] = q; }
  __syncthreads();
  s = rs[0] + rs[1] + rs[2] + rs[3];
  q = rq[0] + rq[1] + rq[2] + rq[3];
  float mean = s * (1.0f / HH);
  float rstd = rsqrtf(q * (1.0f / HH) - mean * mean + 1e-5f);
  #pragma unroll
  for (int j = 0; j < 3; j++) {
    int c = tid + j * 256;
    out[rb + c] = f2bf((v[j] - mean) * rstd * g[c] + bb[c]);
  }
}

// out f32 = sum_{s<4} part_s + bias[col] + res, vectorized x4 (row len 768)
__global__ __launch_bounds__(256)
void reduce4_bias_res(const float* __restrict__ p, const float* __restrict__ bias,
                      const float* __restrict__ res, float* __restrict__ out) {
  int i = (blockIdx.x * 256 + threadIdx.x) * 4;
  int col = i % HH;
  float4 a = *(const float4*)(p + i);
  #pragma unroll
  for (int s = 1; s < 4; s++) {
    float4 b = *(const float4*)(p + (size_t)s * RR * HH + i);
    a.x += b.x; a.y += b.y; a.z += b.z; a.w += b.w;
  }
  float4 bb = *(const float4*)(bias + col);
  float4 r = *(const float4*)(res + i);
  float4 o;
  o.x = a.x + bb.x + r.x;
  o.y = a.y + bb.y + r.y;
  o.z = a.z + bb.z + r.z;
  o.w = a.w + bb.w + r.w;
  *(float4*)(out + i) = o;
}

// ---------------------------------------------------------------------------
// Fused L1-distance (v_sad_u8) + softmax + PV MFMA, v4 = R4 structure
// (LDS-staged K, q-split SAD: proven 65.7us) + two surgical upgrades:
//  (a) P bf16 stored in LDS with XOR swizzle ^((row&7)<<3) [R6-verified:
//      bank conflicts 5.5M -> 786K] so PV's b128 column-slice read hits the
//      8-cycle floor instead of a 16-way conflict;
//  (b) PV uses all 8 waves via k-split: waves 0-3 k=[0,512), waves 4-7
//      k=[512,1024) for the same d-cols; 4KB LDS partial + one barrier to
//      combine. Halves the dependent MFMA accumulate chain.
// ---------------------------------------------------------------------------
#define DQ 16
__global__ __launch_bounds__(512)
void dist_softmax_pv(const unsigned* __restrict__ Qq, const unsigned* __restrict__ Kq,
                     const unsigned short* __restrict__ Vt,
                     const float* __restrict__ lam_p,
                     float* __restrict__ attnF, unsigned short* __restrict__ ctx) {
  __shared__ __align__(16) unsigned lk[8 * SB];     // 32 KB; reused as P bf16 (swizzled)
  __shared__ unsigned lq[DQ * 16];                  // 1 KB: [row][dg]
  __shared__ __align__(16) float pv_part[4][64][4]; // 4 KB: PV k-half partials
  const int bh = blockIdx.y;           // 0..23
  const int q0 = blockIdx.x * DQ;
  const int b = bh / NHH, h = bh % NHH;
  const int tid = threadIdx.x;
  const int w = tid >> 6, lane = tid & 63;
  const int lo = lane & 15, hi = lane >> 4;

  // load pre-quantized Q tile: 16 rows x 16 dgroups
  if (tid < 256) {
    int r = tid >> 4, dg = tid & 15;
    lq[r * 16 + dg] = Qq[(size_t)(b * SB + q0 + r) * 192 + h * 16 + dg];
  }

  const unsigned* Ks = Kq + (size_t)bh * 16 * SB;
  unsigned acc[2][4][4] = {};   // [qi][kg][c]
  const unsigned* lqw = &lq[(w * 2) * 16];

  #pragma unroll
  for (int ch = 0; ch < 2; ch++) {
    #pragma unroll
    for (int i = 0; i < 4; i++)
      async16(&lk[(i * 512 + tid) * 4], Ks + (size_t)ch * 8192 + (i * 512 + tid) * 4);
    __syncthreads();
    #pragma unroll
    for (int dg = 0; dg < 8; dg++) {
      unsigned qd[2];
      #pragma unroll
      for (int qi = 0; qi < 2; qi++) qd[qi] = lqw[qi * 16 + ch * 8 + dg];
      uint4 kv[4];
      #pragma unroll
      for (int kg = 0; kg < 4; kg++)
        kv[kg] = *(const uint4*)&lk[dg * SB + kg * 256 + lane * 4];
      #pragma unroll
      for (int qi = 0; qi < 2; qi++) {
        #pragma unroll
        for (int kg = 0; kg < 4; kg++) {
          acc[qi][kg][0] = __builtin_amdgcn_sad_u8(qd[qi], kv[kg].x, acc[qi][kg][0]);
          acc[qi][kg][1] = __builtin_amdgcn_sad_u8(qd[qi], kv[kg].y, acc[qi][kg][1]);
          acc[qi][kg][2] = __builtin_amdgcn_sad_u8(qd[qi], kv[kg].z, acc[qi][kg][2]);
          acc[qi][kg][3] = __builtin_amdgcn_sad_u8(qd[qi], kv[kg].w, acc[qi][kg][3]);
        }
      }
    }
    __syncthreads();   // all waves done with lk before restage / reuse
  }

  // softmax in-register; write attn f32; store P bf16 into lk (swizzled)
  unsigned short* lp = (unsigned short*)lk;   // [16 q][1024 k] bf16 = 32 KB
  const float kscl = -lam_p[0] * 0.125f / QSCALE;
  #pragma unroll
  for (int qi = 0; qi < 2; qi++) {
    float sc[16];
    float m = -1e30f;
    #pragma unroll
    for (int kg = 0; kg < 4; kg++)
      #pragma unroll
      for (int c = 0; c < 4; c++) {
        float v = (float)acc[qi][kg][c] * kscl;
        sc[kg * 4 + c] = v;
        m = fmaxf(m, v);
      }
    #pragma unroll
    for (int off = 1; off < 64; off <<= 1) m = fmaxf(m, __shfl_xor(m, off));
    float s = 0.f;
    #pragma unroll
    for (int i = 0; i < 16; i++) {
      float e = __expf(sc[i] - m);
      sc[i] = e;
      s += e;
    }
    #pragma unroll
    for (int off = 1; off < 64; off <<= 1) s += __shfl_xor(s, off);
    const float rinv = 1.0f / s;
    const int row = w * 2 + qi;
    const unsigned swz = (unsigned)((row & 7) << 3);   // ushort units = 16B gran
    const size_t gb = (size_t)bh * SB * SB + (size_t)(q0 + row) * SB + lane * 4;
    #pragma unroll
    for (int kg = 0; kg < 4; kg++) {
      float4 p;
      p.x = sc[kg * 4 + 0] * rinv;
      p.y = sc[kg * 4 + 1] * rinv;
      p.z = sc[kg * 4 + 2] * rinv;
      p.w = sc[kg * 4 + 3] * rinv;
      *(float4*)&attnF[gb + kg * 256] = p;
      ushort4 pb;
      pb.x = f2bf(p.x); pb.y = f2bf(p.y); pb.z = f2bf(p.z); pb.w = f2bf(p.w);
      *(ushort4*)&lp[(unsigned)(row * SB + kg * 256 + lane * 4) ^ swz] = pb;
    }
  }
  __syncthreads();   // P complete in LDS

  // PV: all 8 waves. wave w covers d-cols (w&3)*16+lo, k-half (w>>2)*512.
  {
    const int wd = w & 3, kh = w >> 2;
    const unsigned short* Vb = Vt + ((size_t)bh * HDD + wd * 16 + lo) * SB
                             + kh * 512 + hi * 8;
    const unsigned pswz = (unsigned)((lo & 7) << 3);
    const unsigned pbase = (unsigned)(lo * SB + kh * 512 + hi * 8);
    f4 cacc = {0.f, 0.f, 0.f, 0.f};
    #pragma unroll
    for (int k0 = 0; k0 < 512; k0 += 32) {
      short8 af = *(const short8*)&lp[(pbase + k0) ^ pswz];   // A: P[m=lo][k]
      short8 bf = *(const short8*)(Vb + k0);                  // B: Vt[n=col][k]
      cacc = __builtin_amdgcn_mfma_f32_16x16x32_bf16(af, bf, cacc, 0, 0, 0);
    }
    if (w >= 4) *(f4*)&pv_part[wd][lane][0] = cacc;
    __syncthreads();
    if (w < 4) {
      f4 o = *(const f4*)&pv_part[wd][lane][0];
      cacc.x += o.x; cacc.y += o.y; cacc.z += o.z; cacc.w += o.w;
      // D: col=lane&15 -> d = wd*16+lo ; row=(lane>>4)*4+r -> q row
      unsigned short* cb = ctx + (size_t)(b * SB + q0 + hi * 4) * HH
                         + h * HDD + wd * 16 + lo;
      #pragma unroll
      for (int r = 0; r < 4; r++) cb[(size_t)r * HH] = f2bf(cacc[r]);
    }
  }
}

// ---------------------------------------------------------------------------
extern "C" void kernel_launch(void* const* d_in, const int* in_sizes, int n_in,
                              void* d_out, int out_size, void* d_ws, size_t ws_size,
                              hipStream_t stream) {
  (void)in_sizes; (void)n_in; (void)out_size; (void)ws_size;
  const float* hidden = (const float*)d_in[0];
  const float* ln1_g  = (const float*)d_in[1];
  const float* ln1_b  = (const float*)d_in[2];
  const float* Wq     = (const float*)d_in[3];
  const float* bq     = (const float*)d_in[4];
  const float* Wk     = (const float*)d_in[5];
  const float* bk     = (const float*)d_in[6];
  const float* Wv     = (const float*)d_in[7];
  const float* bv     = (const float*)d_in[8];
  const float* Wo     = (const float*)d_in[9];
  const float* bo     = (const float*)d_in[10];
  const float* lam    = (const float*)d_in[11];
  const float* ln2_g  = (const float*)d_in[12];
  const float* ln2_b  = (const float*)d_in[13];
  const float* W1     = (const float*)d_in[14];
  const float* b1     = (const float*)d_in[15];
  const float* W2     = (const float*)d_in[16];
  const float* b2     = (const float*)d_in[17];

  float* out0  = (float*)d_out;                     // [2,1024,768]
  float* attnF = out0 + (size_t)RR * HH;            // [2,12,1024,1024]

  // workspace carve-up (256B aligned)
  char* w = (char*)d_ws;
  auto alloc = [&](size_t bytes) { char* p = w; w += (bytes + 255) & ~(size_t)255; return p; };
  unsigned short* xb      = (unsigned short*)alloc((size_t)RR * HH * 2);       // LN1 out bf16
  unsigned short* Wqkv_t  = (unsigned short*)alloc((size_t)NQKV * HH * 2);     // [2304][768]
  unsigned short* Wo_t    = (unsigned short*)alloc((size_t)HH * HH * 2);       // contiguous after Wqkv_t!
  unsigned short* W1t     = (unsigned short*)alloc((size_t)FFF * HH * 2);      // [3072][768]
  unsigned short* W2t     = (unsigned short*)alloc((size_t)HH * FFF * 2);      // [768][3072]
  float*          bqkv    = (float*)alloc((size_t)NQKV * 4);
  unsigned*       Qq      = (unsigned*)alloc((size_t)RR * 192 * 4);            // u8 [2048][768]
  unsigned*       Kq      = (unsigned*)alloc((size_t)BB * NHH * 16 * SB * 4);  // u8x4 [24][16][1024]
  unsigned short* Vt      = (unsigned short*)alloc((size_t)BB * NHH * HDD * SB * 2); // [24][64][1024]
  unsigned short* ctx     = (unsigned short*)alloc((size_t)RR * HH * 2);       // PV out bf16
  float*          attnOut = (float*)alloc((size_t)RR * HH * 4);                // attn block out f32
  unsigned short* h1      = (unsigned short*)alloc((size_t)RR * FFF * 2);      // FFN1 out bf16
  float*          gPart   = (float*)alloc((size_t)4 * RR * HH * 4);            // split-K partials x4
  unsigned short* y2      = Vt;                     // alias: Vt dead after dist
  (void)Wo_t;

  // ---- 1. prep: weight transposes + bias concat + LN1 (one dispatch)
  prep_all<<<dim3(1737 + RR), 256, 0, stream>>>(Wq, Wk, Wv, Wo, W1, W2, bq, bk, bv,
                                                hidden, ln1_g, ln1_b,
                                                Wqkv_t, W1t, W2t, bqkv, xb);

  // ---- 2. fused QKV GEMM with quantize/transpose epilogue (288 blocks)
  gemm_qkv<<<dim3(NQKV / 128, RR / 128), 256, 0, stream>>>(
      xb, Wqkv_t, bqkv, Qq, Kq, Vt);

  // ---- 3. L1 distance + softmax + PV -> attn f32 (d_out) + ctx bf16
  dist_softmax_pv<<<dim3(SB / DQ, BB * NHH), 512, 0, stream>>>(
      Qq, Kq, Vt, lam, attnF, ctx);

  // ---- 4. output proj, 128x128 split-K x4 (384 blocks): ctx@Wo -> partials
  gemm_bt<128, 128, 2, 2, 4, 4><<<dim3(HH / 128, RR / 128, 4), 256, 0, stream>>>(
      ctx, HH, Wqkv_t + (size_t)3 * HH * HH, HH, gPart, HH,
      nullptr, HH, (long)RR * HH);

  // ---- 5. fused reduce(+bo+hidden) + LN2 -> attnOut f32 + y2 bf16
  reduce_ln<<<dim3(RR), 256, 0, stream>>>(gPart, bo, hidden, ln2_g, ln2_b,
                                          attnOut, y2);

  // ---- 6. FFN1: gelu(y2@W1 + b1) -> bf16 (384 blocks, 128x128)
  gemm_bt<128, 128, 2, 2, 3, 1><<<dim3(FFF / 128, RR / 128, 1), 256, 0, stream>>>(
      y2, HH, W1t, HH, h1, FFF, b1, HH, 0);

  // ---- 7. FFN2, 128x128 split-K x4 (384 blocks): h1@W2 -> partials
  gemm_bt<128, 128, 2, 2, 4, 4><<<dim3(HH / 128, RR / 128, 4), 256, 0, stream>>>(
      h1, FFF, W2t, FFF, gPart, HH, nullptr, FFF, (long)RR * HH);

  // ---- 8. final reduce + b2 + attnOut -> out0
  reduce4_bias_res<<<dim3(RR * HH / 1024), 256, 0, stream>>>(gPart, b2, attnOut, out0);
}

// Round 10
// 281.550 us; speedup vs baseline: 1.4008x; 1.0139x over previous
//
#include <hip/hip_runtime.h>
#include <cstdint>
#include <cstddef>

// Problem constants
#define SB    1024          // sequence
#define BB    2             // batch
#define HH    768           // hidden
#define NHH   12            // heads
#define HDD   64            // head dim
#define FFF   3072          // ffn dim
#define RR    (BB*SB)       // 2048 token rows
#define NQKV  2304          // fused QKV cols

// u8 quantization for L1 distance: x -> round(x*42.5)+128, clamp [0,255].
#define QSCALE 42.5f

typedef __attribute__((ext_vector_type(8))) short short8;   // 8 x bf16 (4 VGPRs)
typedef __attribute__((ext_vector_type(4))) float f4;       // 4 x f32 accumulator

__device__ __forceinline__ unsigned short f2bf(float f) {
  union { float f; unsigned u; } x; x.f = f;
  unsigned r = x.u + 0x7FFFu + ((x.u >> 16) & 1u);   // RNE
  return (unsigned short)(r >> 16);
}

__device__ __forceinline__ unsigned qz8(float x) {
  int v = (int)rintf(x * QSCALE) + 128;
  v = v < 0 ? 0 : (v > 255 ? 255 : v);
  return (unsigned)v;
}

// async global->LDS, 16B per lane. LDS dest = wave-uniform base + lane*16.
__device__ __forceinline__ void async16(void* lds, const void* g) {
  __builtin_amdgcn_global_load_lds((const __attribute__((address_space(1))) unsigned int*)g,
                                   (__attribute__((address_space(3))) unsigned int*)lds,
                                   16, 0, 0);
}

// ---------------------------------------------------------------------------
// Merged prep: weight transposes (blocks 0..1727), bias concat (1728..1736),
// LN1 rows (1737..3784). One dispatch replaces three.
// ---------------------------------------------------------------------------
__global__ __launch_bounds__(256)
void prep_all(const float* __restrict__ Wq, const float* __restrict__ Wk,
              const float* __restrict__ Wv, const float* __restrict__ Wo,
              const float* __restrict__ W1, const float* __restrict__ W2,
              const float* __restrict__ bq, const float* __restrict__ bk,
              const float* __restrict__ bv,
              const float* __restrict__ hidden, const float* __restrict__ ln1_g,
              const float* __restrict__ ln1_b,
              unsigned short* __restrict__ Wqkv_t, unsigned short* __restrict__ W1t,
              unsigned short* __restrict__ W2t, float* __restrict__ bqkv,
              unsigned short* __restrict__ xb) {
  const int t = blockIdx.x;
  const int tid = threadIdx.x;
  __shared__ float tile[64][65];
  __shared__ float rs[4], rq[4];
  if (t >= 1737) {                     // ---- LN1: one row per block
    const int row = t - 1737;
    const float* x = hidden + (size_t)row * HH;
    float v0 = x[tid], v1 = x[tid + 256], v2 = x[tid + 512];
    float s = v0 + v1 + v2;
    float q = v0 * v0 + v1 * v1 + v2 * v2;
    #pragma unroll
    for (int o = 32; o >= 1; o >>= 1) { s += __shfl_xor(s, o); q += __shfl_xor(q, o); }
    const int w = tid >> 6;
    if ((tid & 63) == 0) { rs[w] = s; rq[w] = q; }
    __syncthreads();
    s = rs[0] + rs[1] + rs[2] + rs[3];
    q = rq[0] + rq[1] + rq[2] + rq[3];
    float mean = s * (1.0f / HH);
    float rstd = rsqrtf(q * (1.0f / HH) - mean * mean + 1e-5f);
    unsigned short* o0 = xb + (size_t)row * HH;
    o0[tid]       = f2bf((v0 - mean) * rstd * ln1_g[tid]       + ln1_b[tid]);
    o0[tid + 256] = f2bf((v1 - mean) * rstd * ln1_g[tid + 256] + ln1_b[tid + 256]);
    o0[tid + 512] = f2bf((v2 - mean) * rstd * ln1_g[tid + 512] + ln1_b[tid + 512]);
    return;
  }
  if (t >= 1728) {                     // ---- bias concat
    int i = (t - 1728) * 256 + tid;
    if (i < NQKV)
      bqkv[i] = (i < HH) ? bq[i] : (i < 2 * HH ? bk[i - HH] : bv[i - 2 * HH]);
    return;
  }
  // ---- transpose+cast tiles
  const float* in; unsigned short* out; int ldin, ldout, r0, c0;
  if (t < 576) {                       // 4x 768x768 -> Wqkv_t (+Wo_t after)
    int m = t / 144, q = t % 144;
    in = m == 0 ? Wq : (m == 1 ? Wk : (m == 2 ? Wv : Wo));
    out = Wqkv_t + (size_t)m * HH * HH;
    ldin = HH; ldout = HH;
    r0 = (q / 12) * 64; c0 = (q % 12) * 64;
  } else if (t < 1152) {               // W1 [768][3072]
    int q = t - 576;
    in = W1; out = W1t; ldin = FFF; ldout = HH;
    r0 = (q % 12) * 64; c0 = (q / 12) * 64;
  } else {                             // W2 [3072][768]
    int q = t - 1152;
    in = W2; out = W2t; ldin = HH; ldout = FFF;
    r0 = (q % 48) * 64; c0 = (q / 48) * 64;
  }
  for (int i = tid; i < 4096; i += 256) {
    int r = i >> 6, c = i & 63;
    tile[r][c] = in[(size_t)(r0 + r) * ldin + c0 + c];
  }
  __syncthreads();
  for (int i = tid; i < 4096; i += 256) {
    int cc = i >> 6, rr = i & 63;
    out[(size_t)(c0 + cc) * ldout + r0 + rr] = f2bf(tile[rr][cc]);
  }
}

// ---------------------------------------------------------------------------
// Fused QKV GEMM, 128x128 tile, 4 waves, depth-2 prefetch / 3 LDS buffers
// with counted vmcnt (no full drain in K-loop; critical at ~1 wave/SIMD).
// Epilogue writes, per column region (blockIdx.x/6):
//   0: Qq u8 [2048][768]            (quantized acc+bias)
//   1: Kq u32 [24 bh][16 dg][1024]  (4 packed u8 dims)
//   2: Vt bf16 [24 bh][64 d][1024]  (transposed)
// All via LDS bounce on the dead staging buffers -> coalesced stores.
// ---------------------------------------------------------------------------
__global__ __launch_bounds__(256)
void gemm_qkv(const unsigned short* __restrict__ A, const unsigned short* __restrict__ Bt,
              const float* __restrict__ bqkv, unsigned* __restrict__ Qq,
              unsigned* __restrict__ Kq, unsigned short* __restrict__ Vt) {
  __shared__ __align__(16) unsigned char smem[49152];   // 3x(8K A + 8K B); bounce <=33.3KB
  unsigned short (*lA)[128 * 32] = (unsigned short (*)[128 * 32])smem;
  unsigned short (*lB)[128 * 32] = (unsigned short (*)[128 * 32])(smem + 24576);
  const unsigned short* Ab = A + (size_t)blockIdx.y * 128 * HH;
  const unsigned short* Bb = Bt + (size_t)blockIdx.x * 128 * HH;
  const int tid = threadIdx.x;
  const int wave = tid >> 6, lane = tid & 63;
  const int wr = wave >> 1, wc = wave & 1;
  const int lo = lane & 15, hi = lane >> 4;

  auto stage = [&](int k0, int buf) {
    #pragma unroll
    for (int i = 0; i < 512; i += 256) {
      int idx = i + tid; int r = idx >> 2, kg = idx & 3;
      async16(&lA[buf][idx * 8], &Ab[(size_t)r * HH + k0 + kg * 8]);
    }
    #pragma unroll
    for (int i = 0; i < 512; i += 256) {
      int idx = i + tid; int r = idx >> 2, kg = idx & 3;
      async16(&lB[buf][idx * 8], &Bb[(size_t)r * HH + k0 + kg * 8]);
    }
  };

  stage(0, 0);
  stage(32, 1);                        // 8 loads/thread outstanding
  f4 acc[4][4] = {};
  for (int it = 0; it < 24; it++) {
    if (it + 1 < 24) {
      asm volatile("s_waitcnt vmcnt(4)" ::: "memory");   // stage(it) done
    } else {
      asm volatile("s_waitcnt vmcnt(0)" ::: "memory");
    }
    __builtin_amdgcn_s_barrier();
    __builtin_amdgcn_sched_barrier(0);
    const int cur = it % 3;
    short8 af[4], bf[4];
    #pragma unroll
    for (int i = 0; i < 4; i++)
      af[i] = *(const short8*)&lA[cur][(wr * 64 + i * 16 + lo) * 32 + hi * 8];
    #pragma unroll
    for (int j = 0; j < 4; j++)
      bf[j] = *(const short8*)&lB[cur][(wc * 64 + j * 16 + lo) * 32 + hi * 8];
    if (it + 2 < 24) stage((it + 2) * 32, (it + 2) % 3);
    #pragma unroll
    for (int i = 0; i < 4; i++)
      #pragma unroll
      for (int j = 0; j < 4; j++)
        acc[i][j] = __builtin_amdgcn_mfma_f32_16x16x32_bf16(af[i], bf[j], acc[i][j], 0, 0, 0);
  }
  __syncthreads();                     // all waves done with staging LDS

  const int reg = blockIdx.x / 6;      // 0 Q, 1 K, 2 V
  const int cb = blockIdx.x * 128;     // global col base
  if (reg < 2) {
    // u8 tile, row stride 132 B (u32 stride 33 -> conflict-free column reads)
    unsigned char* t8 = smem;
    #pragma unroll
    for (int i = 0; i < 4; i++)
      #pragma unroll
      for (int j = 0; j < 4; j++) {
        int col = wc * 64 + j * 16 + lo;
        float bv_ = bqkv[cb + col];
        #pragma unroll
        for (int r = 0; r < 4; r++) {
          int row = wr * 64 + i * 16 + hi * 4 + r;
          t8[row * 132 + col] = (unsigned char)qz8(acc[i][j][r] + bv_);
        }
      }
    __syncthreads();
    const unsigned* t32 = (const unsigned*)smem;
    if (reg == 0) {                    // Qq [token][192 u32]
      #pragma unroll
      for (int i0 = 0; i0 < 4096; i0 += 256) {
        int idx = i0 + tid;
        int cw = idx & 31, rw = idx >> 5;
        int token = blockIdx.y * 128 + rw;
        Qq[(size_t)token * 192 + blockIdx.x * 32 + cw] = t32[rw * 33 + cw];
      }
    } else {                           // Kq [bh][dg][k]
      #pragma unroll
      for (int i0 = 0; i0 < 4096; i0 += 256) {
        int idx = i0 + tid;
        int rw = idx & 127, cw = idx >> 7;
        int token = blockIdx.y * 128 + rw;
        int b = token >> 10, k = token & 1023;
        int dgG = (blockIdx.x - 6) * 32 + cw;
        Kq[(size_t)((b * NHH + (dgG >> 4)) * 16 + (dgG & 15)) * SB + k] = t32[rw * 33 + cw];
      }
    }
  } else {
    // bf16 tile transposed [col][row], row-pair u32 stride 65 (pad)
    unsigned short* t16 = (unsigned short*)smem;
    #pragma unroll
    for (int i = 0; i < 4; i++)
      #pragma unroll
      for (int j = 0; j < 4; j++) {
        int col = wc * 64 + j * 16 + lo;
        float bv_ = bqkv[cb + col];
        #pragma unroll
        for (int r = 0; r < 4; r++) {
          int row = wr * 64 + i * 16 + hi * 4 + r;
          t16[col * 130 + row] = f2bf(acc[i][j][r] + bv_);
        }
      }
    __syncthreads();
    const unsigned* tv = (const unsigned*)smem;
    unsigned* VtU = (unsigned*)Vt;
    #pragma unroll
    for (int i0 = 0; i0 < 8192; i0 += 256) {
      int idx = i0 + tid;
      int rp = idx & 63, cw = idx >> 6;
      int gcol = (blockIdx.x - 12) * 128 + cw;
      int h = gcol >> 6, d = gcol & 63;
      int b = blockIdx.y >> 3;
      VtU[(size_t)((b * NHH + h) * HDD + d) * 512 + (blockIdx.y & 7) * 64 + rp] =
          tv[cw * 65 + rp];
    }
  }
}

// ---------------------------------------------------------------------------
// bf16 MFMA GEMM, C = A[M,K] @ Bt[N,K]^T, depth-2 prefetch / 3 LDS buffers,
// counted vmcnt (never drains to 0 in the main loop), one barrier per K-step.
// MODE 3: bf16 C = gelu_exact(acc + bias) ; 4: f32 C = acc (k-split partial,
// non-temporal store: pure streaming traffic, keep it out of L2)
// ---------------------------------------------------------------------------
template<int BM, int BN, int WR, int WC, int MODE, int KS>
__global__ __launch_bounds__(WR*WC*64)
void gemm_bt(const unsigned short* __restrict__ A, int ldA,
             const unsigned short* __restrict__ Bt, int ldB,
             void* __restrict__ Cv, int ldC,
             const float* __restrict__ bias,
             int K, long partStride) {
  constexpr int T = WR * WC * 64;
  constexpr int LPT = (BM * 4 + BN * 4) / T;   // async16 per thread per stage
  __shared__ unsigned short lA[3][BM * 32];
  __shared__ unsigned short lB[3][BN * 32];
  const int ks = blockIdx.z;
  const int KH = K / KS;
  const unsigned short* Ab = A + (size_t)blockIdx.y * BM * ldA + (size_t)ks * KH;
  const unsigned short* Bb = Bt + (size_t)blockIdx.x * BN * ldB + (size_t)ks * KH;
  const long cOff = (long)blockIdx.y * BM * ldC + (long)blockIdx.x * BN
                  + (long)ks * partStride;
  const int tid = threadIdx.x;
  const int wave = tid >> 6, lane = tid & 63;
  const int wr = wave / WC, wc = wave % WC;
  const int lo = lane & 15, hi = lane >> 4;

  auto stage = [&](int k0, int buf) {
    #pragma unroll
    for (int i = 0; i < BM * 4; i += T) {
      int idx = i + tid; int r = idx >> 2, kg = idx & 3;
      async16(&lA[buf][idx * 8], &Ab[(size_t)r * ldA + k0 + kg * 8]);
    }
    #pragma unroll
    for (int i = 0; i < BN * 4; i += T) {
      int idx = i + tid; int r = idx >> 2, kg = idx & 3;
      async16(&lB[buf][idx * 8], &Bb[(size_t)r * ldB + k0 + kg * 8]);
    }
  };

  const int nIter = KH / 32;
  stage(0, 0);
  if (nIter > 1) stage(32, 1);
  f4 acc[4][4] = {};
  for (int it = 0; it < nIter; it++) {
    if (it + 1 < nIter) {
      asm volatile("s_waitcnt vmcnt(%0)" :: "n"(LPT) : "memory");  // stage(it) done
    } else {
      asm volatile("s_waitcnt vmcnt(0)" ::: "memory");
    }
    __builtin_amdgcn_s_barrier();
    __builtin_amdgcn_sched_barrier(0);
    const int cur = it % 3;
    short8 af[4], bf[4];
    #pragma unroll
    for (int i = 0; i < 4; i++)
      af[i] = *(const short8*)&lA[cur][(wr * 64 + i * 16 + lo) * 32 + hi * 8];
    #pragma unroll
    for (int j = 0; j < 4; j++)
      bf[j] = *(const short8*)&lB[cur][(wc * 64 + j * 16 + lo) * 32 + hi * 8];
    if (it + 2 < nIter) stage((it + 2) * 32, (it + 2) % 3);
    #pragma unroll
    for (int i = 0; i < 4; i++)
      #pragma unroll
      for (int j = 0; j < 4; j++)
        acc[i][j] = __builtin_amdgcn_mfma_f32_16x16x32_bf16(af[i], bf[j], acc[i][j], 0, 0, 0);
  }
  float* Cf = (float*)Cv;
  unsigned short* Cb = (unsigned short*)Cv;
  const int bc0 = blockIdx.x * BN;
  #pragma unroll
  for (int i = 0; i < 4; i++) {
    #pragma unroll
    for (int j = 0; j < 4; j++) {
      int col = wc * 64 + j * 16 + lo;
      #pragma unroll
      for (int r = 0; r < 4; r++) {
        int row = wr * 64 + i * 16 + hi * 4 + r;
        size_t idx = (size_t)cOff + (size_t)row * ldC + col;
        float v = acc[i][j][r];
        if constexpr (MODE == 3) {
          float tt = v + bias[bc0 + col];
          Cb[idx] = f2bf(0.5f * tt * (1.0f + erff(tt * 0.70710678118654752f)));
        } else {
          __builtin_nontemporal_store(v, &Cf[idx]);   // k-split partial (streaming)
        }
      }
    }
  }
}

// ---------------------------------------------------------------------------
// Fused split-K reduce + bias + residual + LayerNorm.
// attnOut = sum_{s<4} p_s + bias + res ; out = LN(attnOut)*g + b (bf16).
// One block per row of 768. Partials read non-temporally (read-once stream).
// ---------------------------------------------------------------------------
__global__ __launch_bounds__(256)
void reduce_ln(const float* __restrict__ p, const float* __restrict__ bias,
               const float* __restrict__ res, const float* __restrict__ g,
               const float* __restrict__ bb, float* __restrict__ attnOut,
               unsigned short* __restrict__ out) {
  const int row = blockIdx.x, tid = threadIdx.x;
  const size_t rb = (size_t)row * HH;
  float v[3]; float s = 0.f, q = 0.f;
  #pragma unroll
  for (int j = 0; j < 3; j++) {
    int c = tid + j * 256;
    size_t idx = rb + c;
    float a = __builtin_nontemporal_load(&p[idx])
            + __builtin_nontemporal_load(&p[(size_t)RR * HH + idx])
            + __builtin_nontemporal_load(&p[2 * (size_t)RR * HH + idx])
            + __builtin_nontemporal_load(&p[3 * (size_t)RR * HH + idx])
            + bias[c] + res[idx];
    attnOut[idx] = a;
    v[j] = a; s += a; q += a * a;
  }
  #pragma unroll
  for (int o = 32; o >= 1; o >>= 1) { s += __shfl_xor(s, o); q += __shfl_xor(q, o); }
  __shared__ float rs[4], rq[4];
  const int w = tid >> 6;
  if ((tid & 63) == 0) { rs[w] = s; rq[w] = q; }
  __syncthreads();
  s = rs[0] + rs[1] + rs[2] + rs[3];
  q = rq[0] + rq[1] + rq[2] + rq[3];
  float mean = s * (1.0f / HH);
  float rstd = rsqrtf(q * (1.0f / HH) - mean * mean + 1e-5f);
  #pragma unroll
  for (int j = 0; j < 3; j++) {
    int c = tid + j * 256;
    out[rb + c] = f2bf((v[j] - mean) * rstd * g[c] + bb[c]);
  }
}

// out f32 = sum_{s<4} part_s + bias[col] + res, vectorized x4 (row len 768)
__global__ __launch_bounds__(256)
void reduce4_bias_res(const float* __restrict__ p, const float* __restrict__ bias,
                      const float* __restrict__ res, float* __restrict__ out) {
  int i = (blockIdx.x * 256 + threadIdx.x) * 4;
  int col = i % HH;
  f4 a = __builtin_nontemporal_load((const f4*)(p + i));
  #pragma unroll
  for (int s = 1; s < 4; s++) {
    f4 b = __builtin_nontemporal_load((const f4*)(p + (size_t)s * RR * HH + i));
    a += b;
  }
  const float4 bb = *(const float4*)(bias + col);
  const float4 r = *(const float4*)(res + i);
  float4 o;
  o.x = a.x + bb.x + r.x;
  o.y = a.y + bb.y + r.y;
  o.z = a.z + bb.z + r.z;
  o.w = a.w + bb.w + r.w;
  *(float4*)(out + i) = o;
}

// ---------------------------------------------------------------------------
// Fused L1-distance (v_sad_u8) + softmax + PV MFMA, v5:
// 4 waves x 4 q-rows/wave (256 thr). Rationale: SAD's LDS b128 K-reads are
// replicated per wave (q-split); halving the wave count halves the dominant
// per-CU LDS read traffic while total SAD VALU per CU is unchanged
// (per-lane work doubles, wave count halves). Softmax stays wave-local
// (each wave owns full k for its 4 rows). P stored bf16 in LDS with the
// R6-verified XOR swizzle; PV: 4 waves x 16 d-cols, full-k chain.
// attnF written with non-temporal stores (101 MB stream, avoid L2 thrash).
// ---------------------------------------------------------------------------
#define DQ 16
__global__ __launch_bounds__(256)
void dist_softmax_pv(const unsigned* __restrict__ Qq, const unsigned* __restrict__ Kq,
                     const unsigned short* __restrict__ Vt,
                     const float* __restrict__ lam_p,
                     float* __restrict__ attnF, unsigned short* __restrict__ ctx) {
  __shared__ __align__(16) unsigned lk[8 * SB];   // 32 KB; reused as P bf16 (swizzled)
  __shared__ unsigned lq[DQ * 16];                // 1 KB: [row][dg]
  const int bh = blockIdx.y;           // 0..23
  const int q0 = blockIdx.x * DQ;
  const int b = bh / NHH, h = bh % NHH;
  const int tid = threadIdx.x;
  const int w = tid >> 6, lane = tid & 63;       // w = 0..3
  const int lo = lane & 15, hi = lane >> 4;

  // load pre-quantized Q tile: 16 rows x 16 dgroups (exactly 256 threads)
  {
    int r = tid >> 4, dg = tid & 15;
    lq[r * 16 + dg] = Qq[(size_t)(b * SB + q0 + r) * 192 + h * 16 + dg];
  }

  const unsigned* Ks = Kq + (size_t)bh * 16 * SB;
  unsigned acc[4][4][4] = {};   // [qi][kg][c]
  const unsigned* lqw = &lq[(w * 4) * 16];

  #pragma unroll
  for (int ch = 0; ch < 2; ch++) {
    #pragma unroll
    for (int i = 0; i < 8; i++)
      async16(&lk[(i * 256 + tid) * 4], Ks + (size_t)ch * 8192 + (i * 256 + tid) * 4);
    __syncthreads();
    #pragma unroll
    for (int dg = 0; dg < 8; dg++) {
      unsigned qd[4];
      #pragma unroll
      for (int qi = 0; qi < 4; qi++) qd[qi] = lqw[qi * 16 + ch * 8 + dg];
      uint4 kv[4];
      #pragma unroll
      for (int kg = 0; kg < 4; kg++)
        kv[kg] = *(const uint4*)&lk[dg * SB + kg * 256 + lane * 4];
      #pragma unroll
      for (int qi = 0; qi < 4; qi++) {
        #pragma unroll
        for (int kg = 0; kg < 4; kg++) {
          acc[qi][kg][0] = __builtin_amdgcn_sad_u8(qd[qi], kv[kg].x, acc[qi][kg][0]);
          acc[qi][kg][1] = __builtin_amdgcn_sad_u8(qd[qi], kv[kg].y, acc[qi][kg][1]);
          acc[qi][kg][2] = __builtin_amdgcn_sad_u8(qd[qi], kv[kg].z, acc[qi][kg][2]);
          acc[qi][kg][3] = __builtin_amdgcn_sad_u8(qd[qi], kv[kg].w, acc[qi][kg][3]);
        }
      }
    }
    __syncthreads();   // all waves done with lk before restage / reuse
  }

  // softmax in-register; write attn f32 (non-temporal); P bf16 -> lk (swizzled)
  unsigned short* lp = (unsigned short*)lk;   // [16 q][1024 k] bf16 = 32 KB
  const float kscl = -lam_p[0] * 0.125f / QSCALE;
  #pragma unroll
  for (int qi = 0; qi < 4; qi++) {
    float sc[16];
    float m = -1e30f;
    #pragma unroll
    for (int kg = 0; kg < 4; kg++)
      #pragma unroll
      for (int c = 0; c < 4; c++) {
        float v = (float)acc[qi][kg][c] * kscl;
        sc[kg * 4 + c] = v;
        m = fmaxf(m, v);
      }
    #pragma unroll
    for (int off = 1; off < 64; off <<= 1) m = fmaxf(m, __shfl_xor(m, off));
    float s = 0.f;
    #pragma unroll
    for (int i = 0; i < 16; i++) {
      float e = __expf(sc[i] - m);
      sc[i] = e;
      s += e;
    }
    #pragma unroll
    for (int off = 1; off < 64; off <<= 1) s += __shfl_xor(s, off);
    const float rinv = 1.0f / s;
    const int row = w * 4 + qi;
    const unsigned swz = (unsigned)((row & 7) << 3);   // ushort units = 16B gran
    const size_t gb = (size_t)bh * SB * SB + (size_t)(q0 + row) * SB + lane * 4;
    #pragma unroll
    for (int kg = 0; kg < 4; kg++) {
      f4 p;
      p.x = sc[kg * 4 + 0] * rinv;
      p.y = sc[kg * 4 + 1] * rinv;
      p.z = sc[kg * 4 + 2] * rinv;
      p.w = sc[kg * 4 + 3] * rinv;
      __builtin_nontemporal_store(p, (f4*)&attnF[gb + kg * 256]);
      ushort4 pb;
      pb.x = f2bf(p.x); pb.y = f2bf(p.y); pb.z = f2bf(p.z); pb.w = f2bf(p.w);
      *(ushort4*)&lp[(unsigned)(row * SB + kg * 256 + lane * 4) ^ swz] = pb;
    }
  }
  __syncthreads();   // P complete in LDS

  // PV: 4 waves; wave w covers d-cols w*16..+15, all 16 q rows, K=1024.
  {
    const unsigned short* Vb = Vt + ((size_t)bh * HDD + w * 16 + lo) * SB + hi * 8;
    const unsigned pswz = (unsigned)((lo & 7) << 3);
    const unsigned pbase = (unsigned)(lo * SB + hi * 8);
    f4 cacc = {0.f, 0.f, 0.f, 0.f};
    #pragma unroll
    for (int k0 = 0; k0 < SB; k0 += 32) {
      short8 af = *(const short8*)&lp[(pbase + k0) ^ pswz];   // A: P[m=lo][k]
      short8 bf = *(const short8*)(Vb + k0);                  // B: Vt[n=col][k]
      cacc = __builtin_amdgcn_mfma_f32_16x16x32_bf16(af, bf, cacc, 0, 0, 0);
    }
    // D: col=lane&15 -> d = w*16+lo ; row=(lane>>4)*4+r -> q row
    unsigned short* cb = ctx + (size_t)(b * SB + q0 + hi * 4) * HH + h * HDD + w * 16 + lo;
    #pragma unroll
    for (int r = 0; r < 4; r++) cb[(size_t)r * HH] = f2bf(cacc[r]);
  }
}

// ---------------------------------------------------------------------------
extern "C" void kernel_launch(void* const* d_in, const int* in_sizes, int n_in,
                              void* d_out, int out_size, void* d_ws, size_t ws_size,
                              hipStream_t stream) {
  (void)in_sizes; (void)n_in; (void)out_size; (void)ws_size;
  const float* hidden = (const float*)d_in[0];
  const float* ln1_g  = (const float*)d_in[1];
  const float* ln1_b  = (const float*)d_in[2];
  const float* Wq     = (const float*)d_in[3];
  const float* bq     = (const float*)d_in[4];
  const float* Wk     = (const float*)d_in[5];
  const float* bk     = (const float*)d_in[6];
  const float* Wv     = (const float*)d_in[7];
  const float* bv     = (const float*)d_in[8];
  const float* Wo     = (const float*)d_in[9];
  const float* bo     = (const float*)d_in[10];
  const float* lam    = (const float*)d_in[11];
  const float* ln2_g  = (const float*)d_in[12];
  const float* ln2_b  = (const float*)d_in[13];
  const float* W1     = (const float*)d_in[14];
  const float* b1     = (const float*)d_in[15];
  const float* W2     = (const float*)d_in[16];
  const float* b2     = (const float*)d_in[17];

  float* out0  = (float*)d_out;                     // [2,1024,768]
  float* attnF = out0 + (size_t)RR * HH;            // [2,12,1024,1024]

  // workspace carve-up (256B aligned)
  char* w = (char*)d_ws;
  auto alloc = [&](size_t bytes) { char* p = w; w += (bytes + 255) & ~(size_t)255; return p; };
  unsigned short* xb      = (unsigned short*)alloc((size_t)RR * HH * 2);       // LN1 out bf16
  unsigned short* Wqkv_t  = (unsigned short*)alloc((size_t)NQKV * HH * 2);     // [2304][768]
  unsigned short* Wo_t    = (unsigned short*)alloc((size_t)HH * HH * 2);       // contiguous after Wqkv_t!
  unsigned short* W1t     = (unsigned short*)alloc((size_t)FFF * HH * 2);      // [3072][768]
  unsigned short* W2t     = (unsigned short*)alloc((size_t)HH * FFF * 2);      // [768][3072]
  float*          bqkv    = (float*)alloc((size_t)NQKV * 4);
  unsigned*       Qq      = (unsigned*)alloc((size_t)RR * 192 * 4);            // u8 [2048][768]
  unsigned*       Kq      = (unsigned*)alloc((size_t)BB * NHH * 16 * SB * 4);  // u8x4 [24][16][1024]
  unsigned short* Vt      = (unsigned short*)alloc((size_t)BB * NHH * HDD * SB * 2); // [24][64][1024]
  unsigned short* ctx     = (unsigned short*)alloc((size_t)RR * HH * 2);       // PV out bf16
  float*          attnOut = (float*)alloc((size_t)RR * HH * 4);                // attn block out f32
  unsigned short* h1      = (unsigned short*)alloc((size_t)RR * FFF * 2);      // FFN1 out bf16
  float*          gPart   = (float*)alloc((size_t)4 * RR * HH * 4);            // split-K partials x4
  unsigned short* y2      = Vt;                     // alias: Vt dead after dist
  (void)Wo_t;

  // ---- 1. prep: weight transposes + bias concat + LN1 (one dispatch)
  prep_all<<<dim3(1737 + RR), 256, 0, stream>>>(Wq, Wk, Wv, Wo, W1, W2, bq, bk, bv,
                                                hidden, ln1_g, ln1_b,
                                                Wqkv_t, W1t, W2t, bqkv, xb);

  // ---- 2. fused QKV GEMM with quantize/transpose epilogue (288 blocks)
  gemm_qkv<<<dim3(NQKV / 128, RR / 128), 256, 0, stream>>>(
      xb, Wqkv_t, bqkv, Qq, Kq, Vt);

  // ---- 3. L1 distance + softmax + PV -> attn f32 (d_out) + ctx bf16
  dist_softmax_pv<<<dim3(SB / DQ, BB * NHH), 256, 0, stream>>>(
      Qq, Kq, Vt, lam, attnF, ctx);

  // ---- 4. output proj, 128x128 split-K x4 (384 blocks): ctx@Wo -> partials
  gemm_bt<128, 128, 2, 2, 4, 4><<<dim3(HH / 128, RR / 128, 4), 256, 0, stream>>>(
      ctx, HH, Wqkv_t + (size_t)3 * HH * HH, HH, gPart, HH,
      nullptr, HH, (long)RR * HH);

  // ---- 5. fused reduce(+bo+hidden) + LN2 -> attnOut f32 + y2 bf16
  reduce_ln<<<dim3(RR), 256, 0, stream>>>(gPart, bo, hidden, ln2_g, ln2_b,
                                          attnOut, y2);

  // ---- 6. FFN1: gelu(y2@W1 + b1) -> bf16 (384 blocks, 128x128)
  gemm_bt<128, 128, 2, 2, 3, 1><<<dim3(FFF / 128, RR / 128, 1), 256, 0, stream>>>(
      y2, HH, W1t, HH, h1, FFF, b1, HH, 0);

  // ---- 7. FFN2, 128x128 split-K x4 (384 blocks): h1@W2 -> partials
  gemm_bt<128, 128, 2, 2, 4, 4><<<dim3(HH / 128, RR / 128, 4), 256, 0, stream>>>(
      h1, FFF, W2t, FFF, gPart, HH, nullptr, FFF, (long)RR * HH);

  // ---- 8. final reduce + b2 + attnOut -> out0
  reduce4_bias_res<<<dim3(RR * HH / 1024), 256, 0, stream>>>(gPart, b2, attnOut, out0);
}